// Round 2
// baseline (185.972 us; speedup 1.0000x reference)
//
#include <hip/hip_runtime.h>
#include <hip/hip_bf16.h>
#include <math.h>

#define NB 16
#define NT 96
#define NC 3
#define ND 64
#define NJ 192   // C*D
#define NHID 512
#define NF 48
#define NS 17

// ---------------- K1: mean over (H,W): x[B,T,C,16,16,64] -> xm[B,T,192] ----------------
// One block per (b,t,c): 256*64 floats = 4096 float4. 256 threads x 16 iters, coalesced.
// float4 v = vec[256*k + tid] covers d = 4*(tid&15).. and hw = (tid>>4) + 16*k.
__global__ __launch_bounds__(256) void k_mean(const float* __restrict__ x,
                                              float* __restrict__ xm) {
    const int blk = blockIdx.x;                 // (b*NT+t)*NC + c
    const int tid = threadIdx.x;
    const float4* xin = reinterpret_cast<const float4*>(x) + (size_t)blk * 4096;
    float4 acc = make_float4(0.f, 0.f, 0.f, 0.f);
#pragma unroll
    for (int k = 0; k < 16; ++k) {
        float4 v = xin[k * 256 + tid];
        acc.x += v.x; acc.y += v.y; acc.z += v.z; acc.w += v.w;
    }
    __shared__ float4 sums[256];
    sums[tid] = acc;
    __syncthreads();
    if (tid < 16) {
        float4 tot = make_float4(0.f, 0.f, 0.f, 0.f);
#pragma unroll
        for (int g = 0; g < 16; ++g) {
            float4 v = sums[g * 16 + tid];
            tot.x += v.x; tot.y += v.y; tot.z += v.z; tot.w += v.w;
        }
        const float s = 1.0f / 256.0f;
        tot.x *= s; tot.y *= s; tot.z *= s; tot.w *= s;
        const int c  = blk % NC;
        const int bt = blk / NC;
        float4* out = reinterpret_cast<float4*>(xm + (size_t)bt * NJ + c * ND);
        out[tid] = tot;   // element offset c*64 + 4*tid
    }
}

// ---------------- K2: DFT-first: P[b,f,j] = (1/sqrt(96)) * sum_t xm[b,t,j] e^{-i 2pi (f+1) t /96} ----
// Block per (b,f), 192 threads (one per j). Exact integer angle reduction.
__global__ __launch_bounds__(192) void k_dft(const float* __restrict__ xm,
                                             float* __restrict__ Pre,
                                             float* __restrict__ Pim) {
    const int blk = blockIdx.x;   // b*NF + f
    const int f   = blk % NF;
    const int j   = threadIdx.x;
    const float* xrow = xm + (size_t)(blk / NF) * NT * NJ + j;
    const int fr = f + 1;
    float re = 0.f, im = 0.f;
    const float w = 2.0f * 3.14159265358979323846f / 96.0f;
    for (int t = 0; t < NT; ++t) {
        float xv = xrow[(size_t)t * NJ];
        int m = (fr * t) % NT;          // exact reduction
        float sv, cv;
        sincosf((float)m * w, &sv, &cv);
        re += xv * cv;
        im += xv * sv;
    }
    const float inv = 0.1020620726159657f;  // 1/sqrt(96)
    Pre[(size_t)blk * NJ + j] =  re * inv;
    Pim[(size_t)blk * NJ + j] = -im * inv;
}

// ---------------- K3: amp[b,o,f] = |sum_j in_w[o,j] * P[b,f,j]| ----------------
// One thread per (b,o,f) = 393216 threads; float4 dots; coalesced amp write.
__global__ __launch_bounds__(256) void k_amp(const float* __restrict__ in_w,
                                             const float* __restrict__ Pre,
                                             const float* __restrict__ Pim,
                                             float* __restrict__ amp) {
    const int gid = blockIdx.x * 256 + threadIdx.x;   // (b*512+o)*48+f
    const int f = gid % NF;
    const int o = (gid / NF) % NHID;
    const int b = gid / (NF * NHID);
    const float4* w4 = reinterpret_cast<const float4*>(in_w + (size_t)o * NJ);
    const float4* r4 = reinterpret_cast<const float4*>(Pre + ((size_t)b * NF + f) * NJ);
    const float4* i4 = reinterpret_cast<const float4*>(Pim + ((size_t)b * NF + f) * NJ);
    float re = 0.f, im = 0.f;
#pragma unroll 4
    for (int q = 0; q < NJ / 4; ++q) {
        float4 w = w4[q];
        float4 r = r4[q];
        float4 i = i4[q];
        re += w.x * r.x + w.y * r.y + w.z * r.z + w.w * r.w;
        im += w.x * i.x + w.y * i.y + w.z * i.z + w.w * i.w;
    }
    amp[gid] = sqrtf(re * re + im * im);
}

// ---------------- K4: weights[b,s] = mean_o [ amp.wg + noise*(softplus(amp.wn)+eps) ] ----------------
// Block per b, 512 threads (one per o).
__global__ __launch_bounds__(512) void k_weights(const float* __restrict__ amp,
                                                 const float* __restrict__ w_gate,
                                                 const float* __restrict__ w_noise,
                                                 const float* __restrict__ noise,
                                                 const int* __restrict__ training,
                                                 float* __restrict__ weights) {
    const int b = blockIdx.x;
    const int tid = threadIdx.x;   // o
    __shared__ float wg[NF * NS];
    __shared__ float wn[NF * NS];
    for (int i = tid; i < NF * NS; i += 512) { wg[i] = w_gate[i]; wn[i] = w_noise[i]; }
    __syncthreads();

    const float4* a4 = reinterpret_cast<const float4*>(amp + ((size_t)b * NHID + tid) * NF);
    float aC[NS], aN[NS];
#pragma unroll
    for (int s = 0; s < NS; ++s) { aC[s] = 0.f; aN[s] = 0.f; }
    for (int q = 0; q < NF / 4; ++q) {
        float4 av = a4[q];
        float a[4] = {av.x, av.y, av.z, av.w};
#pragma unroll
        for (int u = 0; u < 4; ++u) {
            const int f = q * 4 + u;
#pragma unroll
            for (int s = 0; s < NS; ++s) {
                aC[s] += a[u] * wg[f * NS + s];
                aN[s] += a[u] * wn[f * NS + s];
            }
        }
    }
    const int tr = training[0];
    const float* nrow = noise + ((size_t)b * NHID + tid) * NS;
    float vals[NS];
#pragma unroll
    for (int s = 0; s < NS; ++s) {
        float v = aC[s];
        if (tr) {
            float xx = aN[s];
            float sp = fmaxf(xx, 0.f) + log1pf(expf(-fabsf(xx)));   // stable softplus
            v += nrow[s] * (sp + 0.01f);
        }
        vals[s] = v;
    }
    // wave butterfly reduce (64 lanes)
#pragma unroll
    for (int s = 0; s < NS; ++s) {
#pragma unroll
        for (int off = 1; off <= 32; off <<= 1)
            vals[s] += __shfl_xor(vals[s], off);
    }
    __shared__ float red[8][NS];
    const int wave = tid >> 6;
    const int lane = tid & 63;
    if (lane == 0) {
#pragma unroll
        for (int s = 0; s < NS; ++s) red[wave][s] = vals[s];
    }
    __syncthreads();
    if (tid < NS) {
        float sum = 0.f;
#pragma unroll
        for (int w = 0; w < 8; ++w) sum += red[w][tid];
        weights[b * NS + tid] = sum * (1.0f / 512.0f);
    }
}

// ---------------- K5: top-k + softmax + scatter -> gates[B,17] ----------------
__global__ __launch_bounds__(64) void k_topk(const float* __restrict__ weights,
                                             const int* __restrict__ top_k,
                                             float* __restrict__ out) {
    const int b = threadIdx.x;
    if (b >= NB) return;
    int k = top_k[0];
    if (k < 1) k = 1;
    if (k > NS) k = NS;
    float w[NS];
#pragma unroll
    for (int s = 0; s < NS; ++s) w[s] = weights[b * NS + s];
    float tv[NS];
    int   ti[NS];
    int used = 0;
    for (int kk = 0; kk < k; ++kk) {
        float best = -INFINITY;
        int bi = 0;
#pragma unroll
        for (int s = 0; s < NS; ++s) {
            if (!((used >> s) & 1) && w[s] > best) { best = w[s]; bi = s; }  // '>' => lowest index on tie
        }
        tv[kk] = best; ti[kk] = bi; used |= (1 << bi);
    }
    const float m = tv[0];   // sorted descending
    float sum = 0.f;
    for (int kk = 0; kk < k; ++kk) { tv[kk] = expf(tv[kk] - m); sum += tv[kk]; }
    float outv[NS];
#pragma unroll
    for (int s = 0; s < NS; ++s) outv[s] = 0.f;
    for (int kk = 0; kk < k; ++kk) outv[ti[kk]] = tv[kk] / sum;
#pragma unroll
    for (int s = 0; s < NS; ++s) out[b * NS + s] = outv[s];
}

extern "C" void kernel_launch(void* const* d_in, const int* in_sizes, int n_in,
                              void* d_out, int out_size, void* d_ws, size_t ws_size,
                              hipStream_t stream) {
    const float* x        = (const float*)d_in[0];
    const float* in_w     = (const float*)d_in[1];
    // d_in[2] = in_b: provably irrelevant (contributes only to the dropped DC bin)
    const float* w_gate   = (const float*)d_in[3];
    const float* w_noise  = (const float*)d_in[4];
    const float* noise    = (const float*)d_in[5];
    const int*   training = (const int*)d_in[6];
    const int*   top_k    = (const int*)d_in[7];
    float* out = (float*)d_out;

    float* ws      = (float*)d_ws;
    float* xm      = ws;                      // 16*96*192      = 294912
    float* Pre     = xm  + (size_t)NB * NT * NJ;          // 16*48*192 = 147456
    float* Pim     = Pre + (size_t)NB * NF * NJ;          // 147456
    float* amp     = Pim + (size_t)NB * NF * NJ;          // 16*512*48 = 393216
    float* weights = amp + (size_t)NB * NHID * NF;        // 16*17     = 272

    k_mean  <<<NB * NT * NC, 256, 0, stream>>>(x, xm);
    k_dft   <<<NB * NF,      192, 0, stream>>>(xm, Pre, Pim);
    k_amp   <<<NB * NHID * NF / 256, 256, 0, stream>>>(in_w, Pre, Pim, amp);
    k_weights<<<NB, 512, 0, stream>>>(amp, w_gate, w_noise, noise, training, weights);
    k_topk  <<<1, 64, 0, stream>>>(weights, top_k, out);
}

// Round 3
// 111.273 us; speedup vs baseline: 1.6713x; 1.6713x over previous
//
#include <hip/hip_runtime.h>
#include <hip/hip_bf16.h>
#include <math.h>

#define NB 16
#define NT 96
#define NC 3
#define ND 64
#define NJ 192   // C*D
#define NHID 512
#define NF 48
#define NS 17

// ---------------- K1: mean over (H,W): x[B,T,C,16,16,64] -> xm[B,T,192] ----------------
// One block per (b,t,c): 256*64 floats = 4096 float4. 256 threads x 16 iters, coalesced.
__global__ __launch_bounds__(256) void k_mean(const float* __restrict__ x,
                                              float* __restrict__ xm) {
    const int blk = blockIdx.x;                 // (b*NT+t)*NC + c
    const int tid = threadIdx.x;
    const float4* xin = reinterpret_cast<const float4*>(x) + (size_t)blk * 4096;
    float4 acc = make_float4(0.f, 0.f, 0.f, 0.f);
#pragma unroll
    for (int k = 0; k < 16; ++k) {
        float4 v = xin[k * 256 + tid];
        acc.x += v.x; acc.y += v.y; acc.z += v.z; acc.w += v.w;
    }
    __shared__ float4 sums[256];
    sums[tid] = acc;
    __syncthreads();
    if (tid < 16) {
        float4 tot = make_float4(0.f, 0.f, 0.f, 0.f);
#pragma unroll
        for (int g = 0; g < 16; ++g) {
            float4 v = sums[g * 16 + tid];
            tot.x += v.x; tot.y += v.y; tot.z += v.z; tot.w += v.w;
        }
        const float s = 1.0f / 256.0f;
        tot.x *= s; tot.y *= s; tot.z *= s; tot.w *= s;
        const int c  = blk % NC;
        const int bt = blk / NC;
        float4* out = reinterpret_cast<float4*>(xm + (size_t)bt * NJ + c * ND);
        out[tid] = tot;   // element offset c*64 + 4*tid
    }
}

// ---------------- K2: DFT-first, TRANSPOSED output: PT[b][j][f] ----------------
// PT[b,j,f] = (1/sqrt96) * sum_t xm[b,t,j] e^{-i 2pi (f+1) t/96}
// Block per (b, jc) with jc = j-chunk of 4; 192 threads = (jj 0..3) x (f 0..47).
// Twiddle table (96 entries) built once in LDS; angle index advances incrementally.
__global__ __launch_bounds__(192) void k_dft(const float* __restrict__ xm,
                                             float* __restrict__ PreT,
                                             float* __restrict__ PimT) {
    const int b  = blockIdx.x / NF;   // 48 j-chunks
    const int jc = blockIdx.x % NF;
    const int tid = threadIdx.x;
    const int f  = tid % 48;
    const int jj = tid / 48;
    __shared__ float xs[NT][4];
    __shared__ float ct[NT], st[NT];
    if (tid < NT) {
        const float w = 2.0f * 3.14159265358979323846f / 96.0f;
        float sv, cv;
        sincosf((float)tid * w, &sv, &cv);
        ct[tid] = cv; st[tid] = sv;
    }
    for (int i = tid; i < NT * 4; i += 192) {
        const int t = i >> 2, j4 = i & 3;
        xs[t][j4] = xm[((size_t)b * NT + t) * NJ + jc * 4 + j4];
    }
    __syncthreads();
    const int fr = f + 1;
    float re = 0.f, im = 0.f;
    int m = 0;
    for (int t = 0; t < NT; ++t) {
        const float xv = xs[t][jj];
        re += xv * ct[m];
        im += xv * st[m];
        m += fr; if (m >= NT) m -= NT;   // m = fr*t mod 96, exact
    }
    const float inv = 0.1020620726159657f;  // 1/sqrt(96)
    const int j = jc * 4 + jj;
    PreT[((size_t)b * NJ + j) * NF + f] =  re * inv;   // lanes f consecutive -> coalesced
    PimT[((size_t)b * NJ + j) * NF + f] = -im * inv;
}

// ---------------- K3: amp[b,o,f] = |sum_j in_w[o,j] * PT[b,j,f]| ----------------
// Thread per (b,o,f). f on consecutive lanes -> PT reads are 4B/lane coalesced;
// in_w reads are wave-broadcast (48 lanes share one address), float4 over j.
__global__ __launch_bounds__(256) void k_amp(const float* __restrict__ in_w,
                                             const float* __restrict__ PreT,
                                             const float* __restrict__ PimT,
                                             float* __restrict__ amp) {
    const int gid = blockIdx.x * 256 + threadIdx.x;   // (b*512+o)*48+f
    const int f = gid % NF;
    const int o = (gid / NF) % NHID;
    const int b = gid / (NF * NHID);
    const float4* w4 = reinterpret_cast<const float4*>(in_w + (size_t)o * NJ);
    const float* pr = PreT + (size_t)b * NJ * NF + f;
    const float* pi = PimT + (size_t)b * NJ * NF + f;
    float re = 0.f, im = 0.f;
#pragma unroll 4
    for (int q = 0; q < NJ / 4; ++q) {
        const float4 w = w4[q];
        const int j0 = q * 4;
        re += w.x * pr[(size_t)(j0    ) * NF];
        re += w.y * pr[(size_t)(j0 + 1) * NF];
        re += w.z * pr[(size_t)(j0 + 2) * NF];
        re += w.w * pr[(size_t)(j0 + 3) * NF];
        im += w.x * pi[(size_t)(j0    ) * NF];
        im += w.y * pi[(size_t)(j0 + 1) * NF];
        im += w.z * pi[(size_t)(j0 + 2) * NF];
        im += w.w * pi[(size_t)(j0 + 3) * NF];
    }
    amp[gid] = sqrtf(re * re + im * im);
}

// ---------------- K4: weights[b,s] = mean_o [ amp.wg + noise*(softplus(amp.wn)+eps) ] ----------------
__global__ __launch_bounds__(512) void k_weights(const float* __restrict__ amp,
                                                 const float* __restrict__ w_gate,
                                                 const float* __restrict__ w_noise,
                                                 const float* __restrict__ noise,
                                                 const int* __restrict__ training,
                                                 float* __restrict__ weights) {
    const int b = blockIdx.x;
    const int tid = threadIdx.x;   // o
    __shared__ float wg[NF * NS];
    __shared__ float wn[NF * NS];
    for (int i = tid; i < NF * NS; i += 512) { wg[i] = w_gate[i]; wn[i] = w_noise[i]; }
    __syncthreads();

    const float4* a4 = reinterpret_cast<const float4*>(amp + ((size_t)b * NHID + tid) * NF);
    float aC[NS], aN[NS];
#pragma unroll
    for (int s = 0; s < NS; ++s) { aC[s] = 0.f; aN[s] = 0.f; }
    for (int q = 0; q < NF / 4; ++q) {
        float4 av = a4[q];
        float a[4] = {av.x, av.y, av.z, av.w};
#pragma unroll
        for (int u = 0; u < 4; ++u) {
            const int ff = q * 4 + u;
#pragma unroll
            for (int s = 0; s < NS; ++s) {
                aC[s] += a[u] * wg[ff * NS + s];
                aN[s] += a[u] * wn[ff * NS + s];
            }
        }
    }
    const int tr = training[0];
    const float* nrow = noise + ((size_t)b * NHID + tid) * NS;
    float vals[NS];
#pragma unroll
    for (int s = 0; s < NS; ++s) {
        float v = aC[s];
        if (tr) {
            float xx = aN[s];
            float sp = fmaxf(xx, 0.f) + log1pf(expf(-fabsf(xx)));   // stable softplus
            v += nrow[s] * (sp + 0.01f);
        }
        vals[s] = v;
    }
#pragma unroll
    for (int s = 0; s < NS; ++s) {
#pragma unroll
        for (int off = 1; off <= 32; off <<= 1)
            vals[s] += __shfl_xor(vals[s], off);
    }
    __shared__ float red[8][NS];
    const int wave = tid >> 6;
    const int lane = tid & 63;
    if (lane == 0) {
#pragma unroll
        for (int s = 0; s < NS; ++s) red[wave][s] = vals[s];
    }
    __syncthreads();
    if (tid < NS) {
        float sum = 0.f;
#pragma unroll
        for (int w = 0; w < 8; ++w) sum += red[w][tid];
        weights[b * NS + tid] = sum * (1.0f / 512.0f);
    }
}

// ---------------- K5: top-k + softmax + scatter -> gates[B,17] ----------------
__global__ __launch_bounds__(64) void k_topk(const float* __restrict__ weights,
                                             const int* __restrict__ top_k,
                                             float* __restrict__ out) {
    const int b = threadIdx.x;
    if (b >= NB) return;
    int k = top_k[0];
    if (k < 1) k = 1;
    if (k > NS) k = NS;
    float w[NS];
#pragma unroll
    for (int s = 0; s < NS; ++s) w[s] = weights[b * NS + s];
    float tv[NS];
    int   ti[NS];
    int used = 0;
    for (int kk = 0; kk < k; ++kk) {
        float best = -INFINITY;
        int bi = 0;
#pragma unroll
        for (int s = 0; s < NS; ++s) {
            if (!((used >> s) & 1) && w[s] > best) { best = w[s]; bi = s; }  // '>' => lowest index on tie
        }
        tv[kk] = best; ti[kk] = bi; used |= (1 << bi);
    }
    const float m = tv[0];   // sorted descending
    float sum = 0.f;
    for (int kk = 0; kk < k; ++kk) { tv[kk] = expf(tv[kk] - m); sum += tv[kk]; }
    float outv[NS];
#pragma unroll
    for (int s = 0; s < NS; ++s) outv[s] = 0.f;
    for (int kk = 0; kk < k; ++kk) outv[ti[kk]] = tv[kk] / sum;
#pragma unroll
    for (int s = 0; s < NS; ++s) out[b * NS + s] = outv[s];
}

extern "C" void kernel_launch(void* const* d_in, const int* in_sizes, int n_in,
                              void* d_out, int out_size, void* d_ws, size_t ws_size,
                              hipStream_t stream) {
    const float* x        = (const float*)d_in[0];
    const float* in_w     = (const float*)d_in[1];
    // d_in[2] = in_b: provably irrelevant (contributes only to the dropped DC bin)
    const float* w_gate   = (const float*)d_in[3];
    const float* w_noise  = (const float*)d_in[4];
    const float* noise    = (const float*)d_in[5];
    const int*   training = (const int*)d_in[6];
    const int*   top_k    = (const int*)d_in[7];
    float* out = (float*)d_out;

    float* ws      = (float*)d_ws;
    float* xm      = ws;                                  // 16*96*192 = 294912
    float* PreT    = xm   + (size_t)NB * NT * NJ;         // 16*192*48 = 147456
    float* PimT    = PreT + (size_t)NB * NJ * NF;         // 147456
    float* amp     = PimT + (size_t)NB * NJ * NF;         // 16*512*48 = 393216
    float* weights = amp  + (size_t)NB * NHID * NF;       // 16*17     = 272

    k_mean   <<<NB * NT * NC, 256, 0, stream>>>(x, xm);
    k_dft    <<<NB * NF,      192, 0, stream>>>(xm, PreT, PimT);
    k_amp    <<<NB * NHID * NF / 256, 256, 0, stream>>>(in_w, PreT, PimT, amp);
    k_weights<<<NB, 512, 0, stream>>>(amp, w_gate, w_noise, noise, training, weights);
    k_topk   <<<1, 64, 0, stream>>>(weights, top_k, out);
}

// Round 4
// 99.914 us; speedup vs baseline: 1.8613x; 1.1137x over previous
//
#include <hip/hip_runtime.h>
#include <hip/hip_bf16.h>
#include <math.h>

#define NB 16
#define NT 96
#define NC 3
#define ND 64
#define NJ 192   // C*D
#define NHID 512
#define NF 48
#define NS 17

// ---------------- K1: mean over (H,W): x[B,T,C,16,16,64] -> xm[B,T,192] ----------------
// One block per (b,t,c): 256*64 floats = 4096 float4. 256 threads x 16 iters, coalesced.
__global__ __launch_bounds__(256) void k_mean(const float* __restrict__ x,
                                              float* __restrict__ xm) {
    const int blk = blockIdx.x;                 // (b*NT+t)*NC + c
    const int tid = threadIdx.x;
    const float4* xin = reinterpret_cast<const float4*>(x) + (size_t)blk * 4096;
    float4 acc = make_float4(0.f, 0.f, 0.f, 0.f);
#pragma unroll
    for (int k = 0; k < 16; ++k) {
        float4 v = xin[k * 256 + tid];
        acc.x += v.x; acc.y += v.y; acc.z += v.z; acc.w += v.w;
    }
    __shared__ float4 sums[256];
    sums[tid] = acc;
    __syncthreads();
    if (tid < 16) {
        float4 tot = make_float4(0.f, 0.f, 0.f, 0.f);
#pragma unroll
        for (int g = 0; g < 16; ++g) {
            float4 v = sums[g * 16 + tid];
            tot.x += v.x; tot.y += v.y; tot.z += v.z; tot.w += v.w;
        }
        const float s = 1.0f / 256.0f;
        tot.x *= s; tot.y *= s; tot.z *= s; tot.w *= s;
        const int c  = blk % NC;
        const int bt = blk / NC;
        float4* out = reinterpret_cast<float4*>(xm + (size_t)bt * NJ + c * ND);
        out[tid] = tot;   // element offset c*64 + 4*tid
    }
}

// ---------------- K2: DFT, interleaved transposed output PT[b][j][f] = float2{re,im} ----
// PT[b,j,f] = (1/sqrt96) * sum_t xm[b,t,j] e^{-i 2pi (f+1) t/96}
// Block per (b, jc), jc = j-chunk of 4; 192 threads = (jj 0..3) x (f 0..47).
__global__ __launch_bounds__(192) void k_dft(const float* __restrict__ xm,
                                             float2* __restrict__ PT) {
    const int b  = blockIdx.x / NF;
    const int jc = blockIdx.x % NF;
    const int tid = threadIdx.x;
    const int f  = tid % 48;
    const int jj = tid / 48;
    __shared__ float xs[NT][4];
    __shared__ float ct[NT], st[NT];
    if (tid < NT) {
        const float w = 2.0f * 3.14159265358979323846f / 96.0f;
        float sv, cv;
        sincosf((float)tid * w, &sv, &cv);
        ct[tid] = cv; st[tid] = sv;
    }
    for (int i = tid; i < NT * 4; i += 192) {
        const int t = i >> 2, j4 = i & 3;
        xs[t][j4] = xm[((size_t)b * NT + t) * NJ + jc * 4 + j4];
    }
    __syncthreads();
    const int fr = f + 1;
    float re = 0.f, im = 0.f;
    int m = 0;
    for (int t = 0; t < NT; ++t) {
        const float xv = xs[t][jj];
        re += xv * ct[m];
        im += xv * st[m];
        m += fr; if (m >= NT) m -= NT;   // m = fr*t mod 96, exact
    }
    const float inv = 0.1020620726159657f;  // 1/sqrt(96)
    const int j = jc * 4 + jj;
    PT[((size_t)b * NJ + j) * NF + f] = make_float2(re * inv, -im * inv);  // coalesced 8B/lane
}

// ---------------- K3: amp[b,o,f] = |sum_j in_w[o,j] * PT[b,j,f]| ----------------
// Grid = (b 16) x (oc 16); block 384 = (o_local 0..7) x (f 0..47); 4 o per thread.
// PT j-chunks (48 j x 48 f float2 = 18.4 KB) + in_w chunks (32 o x 48 j = 6 KB) in LDS.
__global__ __launch_bounds__(384) void k_amp(const float* __restrict__ in_w,
                                             const float2* __restrict__ PT,
                                             float* __restrict__ amp) {
    const int b  = blockIdx.x / 16;
    const int oc = blockIdx.x % 16;
    const int tid = threadIdx.x;
    const int f  = tid % 48;
    const int ol = tid / 48;           // 0..7
    __shared__ float2 pc[48][48];
    __shared__ float  wc[32][48];
    float re[4] = {0.f, 0.f, 0.f, 0.f};
    float im[4] = {0.f, 0.f, 0.f, 0.f};
    const float2* ptb = PT + (size_t)b * NJ * NF;
    for (int j0 = 0; j0 < NJ; j0 += 48) {
        // stage PT chunk: 2304 float2, 6 per thread, coalesced per-row
        for (int i = tid; i < 48 * 48; i += 384) {
            const int jj = i / 48, ff = i % 48;
            pc[jj][ff] = ptb[(size_t)(j0 + jj) * NF + ff];
        }
        // stage W chunk: 1536 floats, 4 per thread
        for (int i = tid; i < 32 * 48; i += 384) {
            const int oo = i / 48, jj = i % 48;
            wc[oo][jj] = in_w[(size_t)(oc * 32 + oo) * NJ + j0 + jj];
        }
        __syncthreads();
#pragma unroll 4
        for (int jj = 0; jj < 48; ++jj) {
            const float2 p = pc[jj][f];
#pragma unroll
            for (int r = 0; r < 4; ++r) {
                const float w = wc[ol + 8 * r][jj];
                re[r] += w * p.x;
                im[r] += w * p.y;
            }
        }
        __syncthreads();
    }
#pragma unroll
    for (int r = 0; r < 4; ++r) {
        const int o = oc * 32 + ol + 8 * r;
        amp[((size_t)b * NHID + o) * NF + f] = sqrtf(re[r] * re[r] + im[r] * im[r]);
    }
}

// ---------------- K4: weights + top-k fused. Block per b, 512 threads (one per o). ----
__global__ __launch_bounds__(512) void k_weights(const float* __restrict__ amp,
                                                 const float* __restrict__ w_gate,
                                                 const float* __restrict__ w_noise,
                                                 const float* __restrict__ noise,
                                                 const int* __restrict__ training,
                                                 const int* __restrict__ top_k,
                                                 float* __restrict__ out) {
    const int b = blockIdx.x;
    const int tid = threadIdx.x;   // o
    // stride-20 padding -> 16B-aligned rows (80 B) so the s-loop vectorizes to ds_read_b128
    __shared__ float wg[NF * 20];
    __shared__ float wn[NF * 20];
    for (int i = tid; i < NF * 20; i += 512) {
        const int ff = i / 20, s = i % 20;
        wg[i] = (s < NS) ? w_gate[ff * NS + s] : 0.f;
        wn[i] = (s < NS) ? w_noise[ff * NS + s] : 0.f;
    }
    __syncthreads();

    const float4* a4 = reinterpret_cast<const float4*>(amp + ((size_t)b * NHID + tid) * NF);
    float aC[NS], aN[NS];
#pragma unroll
    for (int s = 0; s < NS; ++s) { aC[s] = 0.f; aN[s] = 0.f; }
    for (int q = 0; q < NF / 4; ++q) {
        float4 av = a4[q];
        float a[4] = {av.x, av.y, av.z, av.w};
#pragma unroll
        for (int u = 0; u < 4; ++u) {
            const int ff = q * 4 + u;
#pragma unroll
            for (int s = 0; s < NS; ++s) {
                aC[s] += a[u] * wg[ff * 20 + s];
                aN[s] += a[u] * wn[ff * 20 + s];
            }
        }
    }
    const int tr = training[0];
    const float* nrow = noise + ((size_t)b * NHID + tid) * NS;
    float vals[NS];
#pragma unroll
    for (int s = 0; s < NS; ++s) {
        float v = aC[s];
        if (tr) {
            float xx = aN[s];
            float sp = fmaxf(xx, 0.f) + log1pf(expf(-fabsf(xx)));   // stable softplus
            v += nrow[s] * (sp + 0.01f);
        }
        vals[s] = v;
    }
#pragma unroll
    for (int s = 0; s < NS; ++s) {
#pragma unroll
        for (int off = 1; off <= 32; off <<= 1)
            vals[s] += __shfl_xor(vals[s], off);
    }
    __shared__ float red[8][NS];
    __shared__ float wfin[NS];
    const int wave = tid >> 6;
    const int lane = tid & 63;
    if (lane == 0) {
#pragma unroll
        for (int s = 0; s < NS; ++s) red[wave][s] = vals[s];
    }
    __syncthreads();
    if (tid < NS) {
        float sum = 0.f;
#pragma unroll
        for (int w = 0; w < 8; ++w) sum += red[w][tid];
        wfin[tid] = sum * (1.0f / 512.0f);
    }
    __syncthreads();
    if (tid == 0) {
        int k = top_k[0];
        if (k < 1) k = 1;
        if (k > NS) k = NS;
        float w[NS];
#pragma unroll
        for (int s = 0; s < NS; ++s) w[s] = wfin[s];
        float tv[NS];
        int   ti[NS];
        int used = 0;
        for (int kk = 0; kk < k; ++kk) {
            float best = -INFINITY;
            int bi = 0;
#pragma unroll
            for (int s = 0; s < NS; ++s) {
                if (!((used >> s) & 1) && w[s] > best) { best = w[s]; bi = s; } // '>' => lowest idx on tie
            }
            tv[kk] = best; ti[kk] = bi; used |= (1 << bi);
        }
        const float m = tv[0];
        float sum = 0.f;
        for (int kk = 0; kk < k; ++kk) { tv[kk] = expf(tv[kk] - m); sum += tv[kk]; }
        float outv[NS];
#pragma unroll
        for (int s = 0; s < NS; ++s) outv[s] = 0.f;
        for (int kk = 0; kk < k; ++kk) outv[ti[kk]] = tv[kk] / sum;
#pragma unroll
        for (int s = 0; s < NS; ++s) out[b * NS + s] = outv[s];
    }
}

extern "C" void kernel_launch(void* const* d_in, const int* in_sizes, int n_in,
                              void* d_out, int out_size, void* d_ws, size_t ws_size,
                              hipStream_t stream) {
    const float* x        = (const float*)d_in[0];
    const float* in_w     = (const float*)d_in[1];
    // d_in[2] = in_b: irrelevant (contributes only to the dropped DC bin)
    const float* w_gate   = (const float*)d_in[3];
    const float* w_noise  = (const float*)d_in[4];
    const float* noise    = (const float*)d_in[5];
    const int*   training = (const int*)d_in[6];
    const int*   top_k    = (const int*)d_in[7];
    float* out = (float*)d_out;

    float* ws  = (float*)d_ws;
    float*  xm = ws;                                     // 16*96*192 floats = 294912
    float2* PT = (float2*)(xm + (size_t)NB * NT * NJ);   // 16*192*48 float2 = 147456
    float* amp = (float*)(PT + (size_t)NB * NJ * NF);    // 16*512*48 floats = 393216

    k_mean   <<<NB * NT * NC, 256, 0, stream>>>(x, xm);
    k_dft    <<<NB * NF,      192, 0, stream>>>(xm, PT);
    k_amp    <<<NB * 16,      384, 0, stream>>>(in_w, PT, amp);
    k_weights<<<NB,           512, 0, stream>>>(amp, w_gate, w_noise, noise, training, top_k, out);
}